// Round 15
// baseline (370.256 us; speedup 1.0000x reference)
//
#include <hip/hip_runtime.h>
#include <cstdint>

// Problem dims (compile-time)
#define B_DIM 8192
#define IN_DIM 1024
#define H_DIM 2048
#define KC 3072     // IN + H (all GEMMs have K = 3072)
#define NTILES 96   // K-tiles of 32

typedef __attribute__((ext_vector_type(8))) __bf16 bf16x8;
typedef __attribute__((ext_vector_type(4))) float f32x4;

// ---------- helpers ----------
__device__ __forceinline__ unsigned short f2bf(float f) {
  unsigned int u = __float_as_uint(f);
  unsigned int r = (u + 0x7fffu + ((u >> 16) & 1u)) >> 16;
  return (unsigned short)r;
}
__device__ __forceinline__ float bf2f(unsigned short s) {
  return __uint_as_float(((unsigned int)s) << 16);
}
__device__ __forceinline__ float sigmoidf_(float x) {
  return 1.0f / (1.0f + __expf(-x));
}
__device__ __forceinline__ float tanhf_(float x) {
  float xc = fminf(fmaxf(x, -15.f), 15.f);
  float t = __expf(2.f * xc);
  return (t - 1.f) / (t + 1.f);
}
__device__ __forceinline__ void gload16(const unsigned short* g, unsigned short* l) {
  __builtin_amdgcn_global_load_lds(
      (const __attribute__((address_space(1))) unsigned int*)(g),
      (__attribute__((address_space(3))) unsigned int*)(l),
      16, 0, 0);
}

// ---------- fused pack: all fp32->bf16 conversions in one launch ----------
__device__ __forceinline__ void cvt4(const float* s, unsigned short* d) {
  const float4 v = *(const float4*)s;
  ushort4 o;
  o.x = f2bf(v.x); o.y = f2bf(v.y); o.z = f2bf(v.z); o.w = f2bf(v.w);
  *(ushort4*)d = o;
}
__global__ __launch_bounds__(256) void pack_all(
    const float* __restrict__ x, const float* __restrict__ h,
    const float* __restrict__ Wir, const float* __restrict__ Wiz,
    const float* __restrict__ Wih, const float* __restrict__ Whr,
    const float* __restrict__ Whz, const float* __restrict__ Whh,
    unsigned short* __restrict__ xh, unsigned short* __restrict__ Wrz,
    unsigned short* __restrict__ Wh_) {
  const int stride = gridDim.x * 256;
  for (int g = blockIdx.x * 256 + threadIdx.x; g < 11010048; g += stride) {
    if (g < 2097152) {            // x (8192x1024) -> xh[:, :1024]
      int r = g >> 8, c = (g & 255) << 2;
      cvt4(x + (long long)r * 1024 + c, xh + (long long)r * KC + c);
    } else if (g < 6291456) {     // h (8192x2048) -> xh[:, 1024:]
      int gg = g - 2097152; int r = gg >> 9, c = (gg & 511) << 2;
      cvt4(h + (long long)r * 2048 + c, xh + (long long)r * KC + IN_DIM + c);
    } else if (g < 6815744) {     // W_ir -> Wrz[0:2048, :1024]
      int gg = g - 6291456; int r = gg >> 8, c = (gg & 255) << 2;
      cvt4(Wir + (long long)r * 1024 + c, Wrz + (long long)r * KC + c);
    } else if (g < 7864320) {     // W_hr -> Wrz[0:2048, 1024:]
      int gg = g - 6815744; int r = gg >> 9, c = (gg & 511) << 2;
      cvt4(Whr + (long long)r * 2048 + c, Wrz + (long long)r * KC + IN_DIM + c);
    } else if (g < 8388608) {     // W_iz -> Wrz[2048:, :1024]
      int gg = g - 7864320; int r = gg >> 8, c = (gg & 255) << 2;
      cvt4(Wiz + (long long)r * 1024 + c, Wrz + (long long)(r + 2048) * KC + c);
    } else if (g < 9437184) {     // W_hz -> Wrz[2048:, 1024:]
      int gg = g - 8388608; int r = gg >> 9, c = (gg & 511) << 2;
      cvt4(Whz + (long long)r * 2048 + c, Wrz + (long long)(r + 2048) * KC + IN_DIM + c);
    } else if (g < 9961472) {     // W_ih -> Wh[:, :1024]
      int gg = g - 9437184; int r = gg >> 8, c = (gg & 255) << 2;
      cvt4(Wih + (long long)r * 1024 + c, Wh_ + (long long)r * KC + c);
    } else {                      // W_hh -> Wh[:, 1024:]
      int gg = g - 9961472; int r = gg >> 9, c = (gg & 511) << 2;
      cvt4(Whh + (long long)r * 2048 + c, Wh_ + (long long)r * KC + IN_DIM + c);
    }
  }
}

// ---------- 256x256 bf16 GEMM (C = A * W^T), BK=32, 4 LDS slots, 8-phase ----------
// R8/R14 K-loop (best measured: 912 TF/GEMM).
// MODE 3: merged r+z dispatch (512 blocks): blocks 0-255 r-gate, 256-511 z-gate.
// MODE 2: final (h_tilde + output).
#define SB0 __builtin_amdgcn_sched_barrier(0)
#define BAR __builtin_amdgcn_s_barrier()
#define VMC(n) asm volatile("s_waitcnt vmcnt(" #n ")" ::: "memory")
#define PRIO1 __builtin_amdgcn_s_setprio(1)
#define PRIO0 __builtin_amdgcn_s_setprio(0)

#define SLOTA(t) (&lds[(t) & 3][0][0])
#define SLOTB(t) (&lds[(t) & 3][1][0])
#define STAGE_(src, dstregion) gload16((src), (unsigned short*)(dstregion) + tid * 8)

#define RDA(dst, slotp, qmv)                                                        \
  _Pragma("unroll") for (int i_ = 0; i_ < 4; i_++)                                  \
      dst[i_] = *(const bf16x8*)((slotp) + ((wm * 128 + (qmv) * 64 + i_ * 16) << 6) + TC);
#define RDB1(dst, slotp, nf)                                                        \
  dst = *(const bf16x8*)((slotp) + ((wn * 64 + (nf) * 16) << 6) + TC);

#define MFMA8(Aset, Bset, qm, qn)                                                   \
  _Pragma("unroll") for (int i_ = 0; i_ < 4; i_++)                                  \
      _Pragma("unroll") for (int j_ = 0; j_ < 2; j_++)                              \
          acc[(qm) * 4 + i_][(qn) * 2 + j_] = __builtin_amdgcn_mfma_f32_16x16x32_bf16( \
              Aset[i_], Bset[(qn) * 2 + j_], acc[(qm) * 4 + i_][(qn) * 2 + j_], 0, 0, 0);

template <int MODE>
__global__ __launch_bounds__(512) void gemm256(
    const unsigned short* __restrict__ Alo_,  // A source for k-tiles < splitT
    const unsigned short* __restrict__ Ahi_,  // A source for k-tiles >= splitT
    int splitT,
    const unsigned short* __restrict__ Wm,    // N x K bf16 (MODE 3: r-weights; +2048*KC = z-weights)
    int NTILN,
    const float* __restrict__ bias0,          // b_r (MODE 3) / b_h (MODE 2)
    const float* __restrict__ bias1,          // b_z (MODE 3)
    const unsigned short* __restrict__ hx,    // xh (h_prev bf16 at cols IN..KC)
    unsigned short* __restrict__ xa,
    float* __restrict__ zbuf,
    float* __restrict__ out) {
  __shared__ char lds[4][2][16384];  // [slot][A/B][bytes] = 128 KiB

  const int tid = threadIdx.x;
  const int lane = tid & 63;
  const int wave = tid >> 6;
  const int wm = wave >> 2;  // 0..1
  const int wn = wave & 3;   // 0..3

  // Block mapping. MODE 3: zmode = bid>>8 selects gate; swizzle within each
  // 256-block half (cpx = 32). MODE 2: grid 256, same swizzle.
  const int bid = blockIdx.x;
  const int zmode = (MODE == 3) ? (bid >> 8) : 0;
  const int b8 = (MODE == 3) ? (bid & 255) : bid;
  const int swz = (b8 & 7) * 32 + (b8 >> 3);
  const int bn = (swz % NTILN) * 256;
  const int bm = (swz / NTILN) * 256;

  const unsigned short* Wsel = (MODE == 3) ? (Wm + (long long)zmode * 2048 * KC) : Wm;
  const float* bias = (MODE == 3) ? (zmode ? bias1 : bias0) : bias0;

  // ---- read-side thread constants ----
  const int fr = lane & 15;
  const int cq = lane >> 4;  // 16B chunk 0..3
  const int TC = ((fr & ~1) << 6) + (((((fr & 1) << 2) | cq) ^ ((fr >> 1) & 7)) << 4);

  // ---- stage-side constants (inverse of the pair-row swizzle) ----
  const int gs0 = tid;
  const int pp0 = (gs0 & 7) ^ ((gs0 >> 3) & 7);
  const int sr0 = ((gs0 >> 3) << 1) + (pp0 >> 2);
  const int sc0 = pp0 & 3;
  const int gs1 = 512 + tid;
  const int pp1 = (gs1 & 7) ^ ((gs1 >> 3) & 7);
  const int sr1 = ((gs1 >> 3) << 1) + (pp1 >> 2);
  const int sc1 = pp1 & 3;

  const long long offA0 = (long long)(bm + sr0) * KC + sc0 * 8;
  const long long offA1 = (long long)(bm + sr1) * KC + sc1 * 8;
  const long long offB0 = (long long)(bn + sr0) * KC + sc0 * 8;
  const long long offB1 = (long long)(bn + sr1) * KC + sc1 * 8;
  const unsigned short* gAlo0 = Alo_ + offA0;
  const unsigned short* gAhi0 = Ahi_ + offA0;
  const unsigned short* gAlo1 = Alo_ + offA1;
  const unsigned short* gAhi1 = Ahi_ + offA1;
  const unsigned short* gB0 = Wsel + offB0;
  const unsigned short* gB1 = Wsel + offB1;

  f32x4 acc[8][4] = {};

  // ---- prologue: stage tiles 0 and 1 fully (8 loads/thread) ----
  STAGE_(((0 < splitT) ? gAlo0 : gAhi0), SLOTA(0));
  STAGE_(((0 < splitT) ? gAlo1 : gAhi1), SLOTA(0) + 8192);
  STAGE_(gB0, SLOTB(0));
  STAGE_(gB1, SLOTB(0) + 8192);
  STAGE_(((1 < splitT) ? gAlo0 : gAhi0) + 32, SLOTA(1));
  STAGE_(((1 < splitT) ? gAlo1 : gAhi1) + 32, SLOTA(1) + 8192);
  STAGE_(gB0 + 32, SLOTB(1));
  STAGE_(gB1 + 32, SLOTB(1) + 8192);
  VMC(4);  // tile 0 landed; tile 1's 4 loads stay in flight
  BAR;

  bf16x8 ALo0[4], AHi0[4], ALo1[4], AHi1[4], Bf0[4], Bf1[4];
  RDA(ALo0, SLOTA(0), 0);
  RDB1(Bf0[0], SLOTB(0), 0);
  RDB1(Bf0[1], SLOTB(0), 1);

  for (int it = 0; it < NTILES / 2; ++it) {
    const int t0 = it * 2;
    const int t1 = t0 + 1;
    int s0 = t0 + 2; if (s0 > NTILES - 1) s0 = NTILES - 1;
    int s1 = t0 + 3; if (s1 > NTILES - 1) s1 = NTILES - 1;
    char* rA0 = SLOTA(t0); char* rB0 = SLOTB(t0);
    char* rA1 = SLOTA(t1); char* rB1 = SLOTB(t1);
    char* wA2 = SLOTA(t0 + 2); char* wB2 = SLOTB(t0 + 2);
    char* wA3 = SLOTA(t0 + 3); char* wB3 = SLOTB(t0 + 3);
    const unsigned short* sA0_0 = ((s0 < splitT) ? gAlo0 : gAhi0) + s0 * 32;
    const unsigned short* sA0_1 = ((s0 < splitT) ? gAlo1 : gAhi1) + s0 * 32;
    const unsigned short* sA1_0 = ((s1 < splitT) ? gAlo0 : gAhi0) + s1 * 32;
    const unsigned short* sA1_1 = ((s1 < splitT) ? gAlo1 : gAhi1) + s1 * 32;

    // ---- p1: MFMA (0,0) t0 ----
    SB0;
    RDB1(Bf0[2], rB0, 2); RDB1(Bf0[3], rB0, 3);
    STAGE_(sA0_0, wA2);
    SB0; BAR; SB0;
    PRIO1; MFMA8(ALo0, Bf0, 0, 0); PRIO0;
    // ---- p2: MFMA (0,1) t0 ----
    SB0;
    RDA(AHi0, rA0, 1);
    STAGE_(sA0_1, wA2 + 8192);
    SB0; VMC(4); BAR; SB0;
    PRIO1; MFMA8(ALo0, Bf0, 0, 1); PRIO0;
    // ---- p3: MFMA (1,0) t0 ----
    SB0;
    RDA(ALo1, rA1, 0);
    STAGE_(gB0 + s0 * 32, wB2);
    SB0; VMC(3); BAR; SB0;
    PRIO1; MFMA8(AHi0, Bf0, 1, 0); PRIO0;
    // ---- p4: MFMA (1,1) t0 ----
    SB0;
    RDB1(Bf1[0], rB1, 0); RDB1(Bf1[1], rB1, 1);
    STAGE_(gB1 + s0 * 32, wB2 + 8192);
    SB0; BAR; SB0;
    PRIO1; MFMA8(AHi0, Bf0, 1, 1); PRIO0;
    // ---- p5: MFMA (0,0) t1 ----
    SB0;
    RDB1(Bf1[2], rB1, 2); RDB1(Bf1[3], rB1, 3);
    STAGE_(sA1_0, wA3);
    SB0; BAR; SB0;
    PRIO1; MFMA8(ALo1, Bf1, 0, 0); PRIO0;
    // ---- p6: MFMA (0,1) t1 ----
    SB0;
    RDA(AHi1, rA1, 1);
    STAGE_(sA1_1, wA3 + 8192);
    SB0; BAR; SB0;
    PRIO1; MFMA8(ALo1, Bf1, 0, 1); PRIO0;
    // ---- p7: MFMA (1,0) t1 ----
    SB0;
    STAGE_(gB0 + s1 * 32, wB3);
    SB0; VMC(3); BAR; SB0;
    PRIO1; MFMA8(AHi1, Bf1, 1, 0); PRIO0;
    // ---- p8: MFMA (1,1) t1 ; reads roll over to next iteration ----
    SB0;
    RDA(ALo0, wA2, 0);
    RDB1(Bf0[0], wB2, 0); RDB1(Bf0[1], wB2, 1);
    STAGE_(gB1 + s1 * 32, wB3 + 8192);
    SB0; BAR; SB0;
    PRIO1; MFMA8(AHi1, Bf1, 1, 1); PRIO0;
  }

  // ---- fused epilogue. C/D layout: col = lane&15, row = (lane>>4)*4 + reg ----
  const int cr = (lane >> 4) << 2;
  const int cc = lane & 15;
#pragma unroll
  for (int i = 0; i < 8; i++) {
#pragma unroll
    for (int j = 0; j < 4; j++) {
#pragma unroll
      for (int e = 0; e < 4; e++) {
        const int m = bm + wm * 128 + i * 16 + cr + e;
        const int n = bn + wn * 64 + j * 16 + cc;
        const float v = acc[i][j][e];
        if (MODE == 3) {
          const float g2 = sigmoidf_(v + bias[n]);
          if (zmode == 0) {
            const float hh = bf2f(hx[(long long)m * KC + IN_DIM + n]);
            xa[(long long)m * KC + IN_DIM + n] = f2bf(g2 * hh);
          } else {
            zbuf[(long long)m * H_DIM + n] = g2;
          }
        } else {
          const float ht = tanhf_(v + bias[n]);
          const long long off = (long long)m * H_DIM + n;
          const float z = zbuf[off];
          const float hh = bf2f(hx[(long long)m * KC + IN_DIM + n]);
          out[off] = (1.f - z) * hh + z * ht;
        }
      }
    }
  }
}

extern "C" void kernel_launch(void* const* d_in, const int* in_sizes, int n_in,
                              void* d_out, int out_size, void* d_ws, size_t ws_size,
                              hipStream_t stream) {
  const float* x    = (const float*)d_in[0];   // (B, IN)
  const float* h    = (const float*)d_in[1];   // (B, H)
  const float* W_ir = (const float*)d_in[2];   // (H, IN)
  const float* W_iz = (const float*)d_in[3];
  const float* W_ih = (const float*)d_in[4];
  const float* W_hr = (const float*)d_in[5];   // (H, H)
  const float* W_hz = (const float*)d_in[6];
  const float* W_hh = (const float*)d_in[7];
  const float* b_r  = (const float*)d_in[8];
  const float* b_z  = (const float*)d_in[9];
  const float* b_h  = (const float*)d_in[10];
  float* out = (float*)d_out;

  // workspace layout (bytes)
  char* ws = (char*)d_ws;
  unsigned short* xh  = (unsigned short*)(ws);                      // B x KC bf16
  unsigned short* xa  = (unsigned short*)(ws + 50331648LL);         // B x KC bf16 (k>=IN region used)
  unsigned short* Wrz = (unsigned short*)(ws + 100663296LL);        // 2H x KC bf16
  unsigned short* Wh  = (unsigned short*)(ws + 125829120LL);        // H x KC bf16
  // z is stashed fp32 in d_out between RZ and GEMM_B.

  // ---- single fused pack ----
  pack_all<<<4096, 256, 0, stream>>>(x, h, W_ir, W_iz, W_ih, W_hr, W_hz, W_hh,
                                     xh, Wrz, Wh);

  const int ntiln = 2048 / 256;               // 8

  // ---- merged GEMM_RZ: 512 blocks; 0-255 r-gate (a=r*h -> xa), 256-511 z-gate (-> d_out) ----
  gemm256<3><<<dim3(512), 512, 0, stream>>>(xh, xh, 0, Wrz, ntiln,
                                            b_r, b_z, xh, xa, out, nullptr);
  // ---- GEMM_B: [x (xh) | a (xa)] @ Wh^T -> h_tilde; final h_t ----
  gemm256<2><<<dim3(256), 512, 0, stream>>>(xh, xa, IN_DIM / 32, Wh, ntiln,
                                            b_h, nullptr, xh, nullptr, out, out);
}

// Round 17
// 343.514 us; speedup vs baseline: 1.0778x; 1.0778x over previous
//
#include <hip/hip_runtime.h>
#include <cstdint>

// Problem dims (compile-time)
#define B_DIM 8192
#define IN_DIM 1024
#define H_DIM 2048
#define KC 3072     // IN + H (all GEMMs have K = 3072)
#define NTILES 96   // K-tiles of 32

typedef __attribute__((ext_vector_type(8))) __bf16 bf16x8;
typedef __attribute__((ext_vector_type(4))) float f32x4;

// ---------- helpers ----------
__device__ __forceinline__ unsigned short f2bf(float f) {
  unsigned int u = __float_as_uint(f);
  unsigned int r = (u + 0x7fffu + ((u >> 16) & 1u)) >> 16;
  return (unsigned short)r;
}
__device__ __forceinline__ float bf2f(unsigned short s) {
  return __uint_as_float(((unsigned int)s) << 16);
}
__device__ __forceinline__ float sigmoidf_(float x) {
  return 1.0f / (1.0f + __expf(-x));
}
__device__ __forceinline__ float tanhf_(float x) {
  float xc = fminf(fmaxf(x, -15.f), 15.f);
  float t = __expf(2.f * xc);
  return (t - 1.f) / (t + 1.f);
}
__device__ __forceinline__ void gload16(const unsigned short* g, unsigned short* l) {
  __builtin_amdgcn_global_load_lds(
      (const __attribute__((address_space(1))) unsigned int*)(g),
      (__attribute__((address_space(3))) unsigned int*)(l),
      16, 0, 0);
}

// ---------- fused pack: all fp32->bf16 conversions in one launch ----------
__device__ __forceinline__ void cvt4(const float* s, unsigned short* d) {
  const float4 v = *(const float4*)s;
  ushort4 o;
  o.x = f2bf(v.x); o.y = f2bf(v.y); o.z = f2bf(v.z); o.w = f2bf(v.w);
  *(ushort4*)d = o;
}
__global__ __launch_bounds__(256) void pack_all(
    const float* __restrict__ x, const float* __restrict__ h,
    const float* __restrict__ Wir, const float* __restrict__ Wiz,
    const float* __restrict__ Wih, const float* __restrict__ Whr,
    const float* __restrict__ Whz, const float* __restrict__ Whh,
    unsigned short* __restrict__ xh, unsigned short* __restrict__ Wrz,
    unsigned short* __restrict__ Wh_) {
  const int stride = gridDim.x * 256;
  for (int g = blockIdx.x * 256 + threadIdx.x; g < 11010048; g += stride) {
    if (g < 2097152) {            // x (8192x1024) -> xh[:, :1024]
      int r = g >> 8, c = (g & 255) << 2;
      cvt4(x + (long long)r * 1024 + c, xh + (long long)r * KC + c);
    } else if (g < 6291456) {     // h (8192x2048) -> xh[:, 1024:]
      int gg = g - 2097152; int r = gg >> 9, c = (gg & 511) << 2;
      cvt4(h + (long long)r * 2048 + c, xh + (long long)r * KC + IN_DIM + c);
    } else if (g < 6815744) {     // W_ir -> Wrz[0:2048, :1024]
      int gg = g - 6291456; int r = gg >> 8, c = (gg & 255) << 2;
      cvt4(Wir + (long long)r * 1024 + c, Wrz + (long long)r * KC + c);
    } else if (g < 7864320) {     // W_hr -> Wrz[0:2048, 1024:]
      int gg = g - 6815744; int r = gg >> 9, c = (gg & 511) << 2;
      cvt4(Whr + (long long)r * 2048 + c, Wrz + (long long)r * KC + IN_DIM + c);
    } else if (g < 8388608) {     // W_iz -> Wrz[2048:, :1024]
      int gg = g - 7864320; int r = gg >> 8, c = (gg & 255) << 2;
      cvt4(Wiz + (long long)r * 1024 + c, Wrz + (long long)(r + 2048) * KC + c);
    } else if (g < 9437184) {     // W_hz -> Wrz[2048:, 1024:]
      int gg = g - 8388608; int r = gg >> 9, c = (gg & 511) << 2;
      cvt4(Whz + (long long)r * 2048 + c, Wrz + (long long)(r + 2048) * KC + IN_DIM + c);
    } else if (g < 9961472) {     // W_ih -> Wh[:, :1024]
      int gg = g - 9437184; int r = gg >> 8, c = (gg & 255) << 2;
      cvt4(Wih + (long long)r * 1024 + c, Wh_ + (long long)r * KC + c);
    } else {                      // W_hh -> Wh[:, 1024:]
      int gg = g - 9961472; int r = gg >> 9, c = (gg & 511) << 2;
      cvt4(Whh + (long long)r * 2048 + c, Wh_ + (long long)r * KC + IN_DIM + c);
    }
  }
}

// ---------- 256x256 bf16 GEMM (C = A * W^T), BK=32, 4 LDS slots, 8-phase ----------
// R8/R14 configuration — best measured (347/349 us total; 912 TF/GEMM).
#define SB0 __builtin_amdgcn_sched_barrier(0)
#define BAR __builtin_amdgcn_s_barrier()
#define VMC(n) asm volatile("s_waitcnt vmcnt(" #n ")" ::: "memory")
#define PRIO1 __builtin_amdgcn_s_setprio(1)
#define PRIO0 __builtin_amdgcn_s_setprio(0)

#define SLOTA(t) (&lds[(t) & 3][0][0])
#define SLOTB(t) (&lds[(t) & 3][1][0])
#define STAGE_(src, dstregion) gload16((src), (unsigned short*)(dstregion) + tid * 8)

#define RDA(dst, slotp, qmv)                                                        \
  _Pragma("unroll") for (int i_ = 0; i_ < 4; i_++)                                  \
      dst[i_] = *(const bf16x8*)((slotp) + ((wm * 128 + (qmv) * 64 + i_ * 16) << 6) + TC);
#define RDB1(dst, slotp, nf)                                                        \
  dst = *(const bf16x8*)((slotp) + ((wn * 64 + (nf) * 16) << 6) + TC);

#define MFMA8(Aset, Bset, qm, qn)                                                   \
  _Pragma("unroll") for (int i_ = 0; i_ < 4; i_++)                                  \
      _Pragma("unroll") for (int j_ = 0; j_ < 2; j_++)                              \
          acc[(qm) * 4 + i_][(qn) * 2 + j_] = __builtin_amdgcn_mfma_f32_16x16x32_bf16( \
              Aset[i_], Bset[(qn) * 2 + j_], acc[(qm) * 4 + i_][(qn) * 2 + j_], 0, 0, 0);

// MODE 0: a = sigmoid(v+b)*h  -> xa[m*KC+IN+n] (bf16)   (r-gate)
// MODE 1: z = sigmoid(v+b)    -> zbuf[m*H+n]   (fp32)   (z-gate)
// MODE 2: ht = tanh(v+b); out = (1-z)*h + z*ht          (final)
template <int MODE>
__global__ __launch_bounds__(512) void gemm256(
    const unsigned short* __restrict__ Alo_,  // A source for k-tiles < splitT
    const unsigned short* __restrict__ Ahi_,  // A source for k-tiles >= splitT
    int splitT,
    const unsigned short* __restrict__ Wm,    // N x K bf16
    int NTILN,
    const float* __restrict__ bias0,
    const unsigned short* __restrict__ hx,    // xh (h_prev bf16 at cols IN..KC)
    unsigned short* __restrict__ xa,
    float* __restrict__ zbuf,
    float* __restrict__ out) {
  __shared__ char lds[4][2][16384];  // [slot][A/B][bytes] = 128 KiB

  const int tid = threadIdx.x;
  const int lane = tid & 63;
  const int wave = tid >> 6;
  const int wm = wave >> 2;  // 0..1
  const int wn = wave & 3;   // 0..3

  // R3 XCD swizzle (grid % 8 == 0)
  const int nwg = gridDim.x;
  const int cpx = nwg >> 3;
  const int bid = blockIdx.x;
  const int swz = (bid & 7) * cpx + (bid >> 3);
  const int bn = (swz % NTILN) * 256;
  const int bm = (swz / NTILN) * 256;

  // ---- read-side thread constants ----
  const int fr = lane & 15;
  const int cq = lane >> 4;  // 16B chunk 0..3
  const int TC = ((fr & ~1) << 6) + (((((fr & 1) << 2) | cq) ^ ((fr >> 1) & 7)) << 4);

  // ---- stage-side constants (inverse of the pair-row swizzle) ----
  const int gs0 = tid;
  const int pp0 = (gs0 & 7) ^ ((gs0 >> 3) & 7);
  const int sr0 = ((gs0 >> 3) << 1) + (pp0 >> 2);
  const int sc0 = pp0 & 3;
  const int gs1 = 512 + tid;
  const int pp1 = (gs1 & 7) ^ ((gs1 >> 3) & 7);
  const int sr1 = ((gs1 >> 3) << 1) + (pp1 >> 2);
  const int sc1 = pp1 & 3;

  const long long offA0 = (long long)(bm + sr0) * KC + sc0 * 8;
  const long long offA1 = (long long)(bm + sr1) * KC + sc1 * 8;
  const long long offB0 = (long long)(bn + sr0) * KC + sc0 * 8;
  const long long offB1 = (long long)(bn + sr1) * KC + sc1 * 8;
  const unsigned short* gAlo0 = Alo_ + offA0;
  const unsigned short* gAhi0 = Ahi_ + offA0;
  const unsigned short* gAlo1 = Alo_ + offA1;
  const unsigned short* gAhi1 = Ahi_ + offA1;
  const unsigned short* gB0 = Wm + offB0;
  const unsigned short* gB1 = Wm + offB1;

  f32x4 acc[8][4] = {};

  // ---- prologue: stage tiles 0 and 1 fully (8 loads/thread) ----
  STAGE_(((0 < splitT) ? gAlo0 : gAhi0), SLOTA(0));
  STAGE_(((0 < splitT) ? gAlo1 : gAhi1), SLOTA(0) + 8192);
  STAGE_(gB0, SLOTB(0));
  STAGE_(gB1, SLOTB(0) + 8192);
  STAGE_(((1 < splitT) ? gAlo0 : gAhi0) + 32, SLOTA(1));
  STAGE_(((1 < splitT) ? gAlo1 : gAhi1) + 32, SLOTA(1) + 8192);
  STAGE_(gB0 + 32, SLOTB(1));
  STAGE_(gB1 + 32, SLOTB(1) + 8192);
  VMC(4);  // tile 0 landed; tile 1's 4 loads stay in flight
  BAR;

  bf16x8 ALo0[4], AHi0[4], ALo1[4], AHi1[4], Bf0[4], Bf1[4];
  RDA(ALo0, SLOTA(0), 0);
  RDB1(Bf0[0], SLOTB(0), 0);
  RDB1(Bf0[1], SLOTB(0), 1);

  for (int it = 0; it < NTILES / 2; ++it) {
    const int t0 = it * 2;
    const int t1 = t0 + 1;
    int s0 = t0 + 2; if (s0 > NTILES - 1) s0 = NTILES - 1;
    int s1 = t0 + 3; if (s1 > NTILES - 1) s1 = NTILES - 1;
    char* rA0 = SLOTA(t0); char* rB0 = SLOTB(t0);
    char* rA1 = SLOTA(t1); char* rB1 = SLOTB(t1);
    char* wA2 = SLOTA(t0 + 2); char* wB2 = SLOTB(t0 + 2);
    char* wA3 = SLOTA(t0 + 3); char* wB3 = SLOTB(t0 + 3);
    const unsigned short* sA0_0 = ((s0 < splitT) ? gAlo0 : gAhi0) + s0 * 32;
    const unsigned short* sA0_1 = ((s0 < splitT) ? gAlo1 : gAhi1) + s0 * 32;
    const unsigned short* sA1_0 = ((s1 < splitT) ? gAlo0 : gAhi0) + s1 * 32;
    const unsigned short* sA1_1 = ((s1 < splitT) ? gAlo1 : gAhi1) + s1 * 32;

    // ---- p1: MFMA (0,0) t0 ----
    SB0;
    RDB1(Bf0[2], rB0, 2); RDB1(Bf0[3], rB0, 3);
    STAGE_(sA0_0, wA2);
    SB0; BAR; SB0;
    PRIO1; MFMA8(ALo0, Bf0, 0, 0); PRIO0;
    // ---- p2: MFMA (0,1) t0 ----
    SB0;
    RDA(AHi0, rA0, 1);
    STAGE_(sA0_1, wA2 + 8192);
    SB0; VMC(4); BAR; SB0;
    PRIO1; MFMA8(ALo0, Bf0, 0, 1); PRIO0;
    // ---- p3: MFMA (1,0) t0 ----
    SB0;
    RDA(ALo1, rA1, 0);
    STAGE_(gB0 + s0 * 32, wB2);
    SB0; VMC(3); BAR; SB0;
    PRIO1; MFMA8(AHi0, Bf0, 1, 0); PRIO0;
    // ---- p4: MFMA (1,1) t0 ----
    SB0;
    RDB1(Bf1[0], rB1, 0); RDB1(Bf1[1], rB1, 1);
    STAGE_(gB1 + s0 * 32, wB2 + 8192);
    SB0; BAR; SB0;
    PRIO1; MFMA8(AHi0, Bf0, 1, 1); PRIO0;
    // ---- p5: MFMA (0,0) t1 ----
    SB0;
    RDB1(Bf1[2], rB1, 2); RDB1(Bf1[3], rB1, 3);
    STAGE_(sA1_0, wA3);
    SB0; BAR; SB0;
    PRIO1; MFMA8(ALo1, Bf1, 0, 0); PRIO0;
    // ---- p6: MFMA (0,1) t1 ----
    SB0;
    RDA(AHi1, rA1, 1);
    STAGE_(sA1_1, wA3 + 8192);
    SB0; BAR; SB0;
    PRIO1; MFMA8(ALo1, Bf1, 0, 1); PRIO0;
    // ---- p7: MFMA (1,0) t1 ----
    SB0;
    STAGE_(gB0 + s1 * 32, wB3);
    SB0; VMC(3); BAR; SB0;
    PRIO1; MFMA8(AHi1, Bf1, 1, 0); PRIO0;
    // ---- p8: MFMA (1,1) t1 ; reads roll over to next iteration ----
    SB0;
    RDA(ALo0, wA2, 0);
    RDB1(Bf0[0], wB2, 0); RDB1(Bf0[1], wB2, 1);
    STAGE_(gB1 + s1 * 32, wB3 + 8192);
    SB0; BAR; SB0;
    PRIO1; MFMA8(AHi1, Bf1, 1, 1); PRIO0;
  }

  // ---- fused epilogue. C/D layout: col = lane&15, row = (lane>>4)*4 + reg ----
  const int cr = (lane >> 4) << 2;
  const int cc = lane & 15;
#pragma unroll
  for (int i = 0; i < 8; i++) {
#pragma unroll
    for (int j = 0; j < 4; j++) {
#pragma unroll
      for (int e = 0; e < 4; e++) {
        const int m = bm + wm * 128 + i * 16 + cr + e;
        const int n = bn + wn * 64 + j * 16 + cc;
        const float v = acc[i][j][e];
        if (MODE == 0) {
          const float g2 = sigmoidf_(v + bias0[n]);
          const float hh = bf2f(hx[(long long)m * KC + IN_DIM + n]);
          xa[(long long)m * KC + IN_DIM + n] = f2bf(g2 * hh);
        } else if (MODE == 1) {
          zbuf[(long long)m * H_DIM + n] = sigmoidf_(v + bias0[n]);
        } else {
          const float ht = tanhf_(v + bias0[n]);
          const long long off = (long long)m * H_DIM + n;
          const float z = zbuf[off];
          const float hh = bf2f(hx[(long long)m * KC + IN_DIM + n]);
          out[off] = (1.f - z) * hh + z * ht;
        }
      }
    }
  }
}

extern "C" void kernel_launch(void* const* d_in, const int* in_sizes, int n_in,
                              void* d_out, int out_size, void* d_ws, size_t ws_size,
                              hipStream_t stream) {
  const float* x    = (const float*)d_in[0];   // (B, IN)
  const float* h    = (const float*)d_in[1];   // (B, H)
  const float* W_ir = (const float*)d_in[2];   // (H, IN)
  const float* W_iz = (const float*)d_in[3];
  const float* W_ih = (const float*)d_in[4];
  const float* W_hr = (const float*)d_in[5];   // (H, H)
  const float* W_hz = (const float*)d_in[6];
  const float* W_hh = (const float*)d_in[7];
  const float* b_r  = (const float*)d_in[8];
  const float* b_z  = (const float*)d_in[9];
  const float* b_h  = (const float*)d_in[10];
  float* out = (float*)d_out;

  // workspace layout (bytes)
  char* ws = (char*)d_ws;
  unsigned short* xh  = (unsigned short*)(ws);                      // B x KC bf16
  unsigned short* xa  = (unsigned short*)(ws + 50331648LL);         // B x KC bf16 (k>=IN region used)
  unsigned short* Wrz = (unsigned short*)(ws + 100663296LL);        // 2H x KC bf16
  unsigned short* Wh  = (unsigned short*)(ws + 125829120LL);        // H x KC bf16
  // z is stashed fp32 in d_out between GEMM_Z and GEMM_B.

  // ---- single fused pack ----
  pack_all<<<4096, 256, 0, stream>>>(x, h, W_ir, W_iz, W_ih, W_hr, W_hz, W_hh,
                                     xh, Wrz, Wh);

  const int ntiln = 2048 / 256;               // 8 -> grid 256 (%8==0), 1 block/CU
  dim3 grid((B_DIM / 256) * ntiln);

  // ---- GEMM_R: [x|h] @ Wr^T -> r-gate; writes a = r*h into xa ----
  gemm256<0><<<grid, 512, 0, stream>>>(xh, xh, 0, Wrz, ntiln,
                                       b_r, xh, xa, nullptr, nullptr);
  // ---- GEMM_Z: [x|h] @ Wz^T -> z-gate; writes z (fp32) into d_out ----
  gemm256<1><<<grid, 512, 0, stream>>>(xh, xh, 0, Wrz + (long long)2048 * KC, ntiln,
                                       b_z, xh, nullptr, out, nullptr);
  // ---- GEMM_B: [x (xh) | a (xa)] @ Wh^T -> h_tilde; final h_t ----
  gemm256<2><<<grid, 512, 0, stream>>>(xh, xa, IN_DIM / 32, Wh, ntiln,
                                       b_h, xh, nullptr, out, out);
}